// Round 4
// baseline (327.151 us; speedup 1.0000x reference)
//
#include <hip/hip_runtime.h>
#include <math.h>

// MoE top-1 gate + per-expert tanh-attention pooling, MI355X (gfx950).
//
// Algorithmic core: reference computes h=[E,N,H] for ALL (expert,token) pairs
// but the masked softmax keeps only sel[n]==e entries -> compute each token's
// score ONLY for its routed expert (34.4 GFLOP instead of 275). b2 drops out
// (softmax shift invariance).
//
// Numerics: gate/argmax fp32 (discrete routing decision must match fp32
// reference); score GEMM bf16 MFMA (smooth ~0.4% score error washes out
// through softmax-weighted pooling); softmax + pooling fp32.
//
// Pipeline: k_gate (gate+argmax+compaction, writes Xbf bf16) -> k_w1t
// (W1 [E][D][H] f32 -> [E][H][D] bf16) -> k_score (grouped MFMA GEMM,
// global_load_lds staging w/ pre-swizzled source) -> k_stats -> k_pool.

#define NTOK 32768
#define DDIM 1024
#define HDIM 512
#define NEXP 8

typedef __attribute__((ext_vector_type(8))) short short8;   // 8 bf16 (MFMA A/B frag)
typedef __attribute__((ext_vector_type(4))) float f32x4;    // MFMA C/D frag

static __device__ __forceinline__ unsigned short f2bf(float f) {
    // round-to-nearest-even fp32 -> bf16
    unsigned int u = __builtin_bit_cast(unsigned int, f);
    unsigned int r = (u + 0x7FFFu + ((u >> 16) & 1u)) >> 16;
    return (unsigned short)r;
}

static __device__ __forceinline__ float fast_tanh(float v) {
    // tanh(v) = 1 - 2/(exp(2v)+1)
    return 1.0f - 2.0f / (__expf(2.0f * v) + 1.0f);
}

// async global->LDS, 16B/lane. HW semantics: LDS dest = wave-uniform base +
// lane*16 (m104/m108). We keep LDS linear and pre-swizzle the GLOBAL source
// address (m173 pattern) so the XOR-swizzled read side stays conflict-free
// (G21: source permutation == read permutation, both-sides-or-neither).
static __device__ __forceinline__ void gload_lds16(const void* g, void* l) {
    __builtin_amdgcn_global_load_lds(
        (const __attribute__((address_space(1))) void*)g,
        (__attribute__((address_space(3))) void*)l, 16, 0, 0);
}

// ---------------------------------------------------------------------------
// Kernel 1: fp32 gate logits, argmax routing, per-expert index compaction,
// and X fp32->bf16 conversion (Xbf) for the score GEMM.
// 1024 blocks x 256 thr (4 blocks/CU -> 16 waves/CU for HBM latency hiding);
// each wave handles 8 tokens sequentially, FULL 1024-f row (4 float4 chunks
// per lane). Atomics aggregated per block (G12).
// ---------------------------------------------------------------------------
__global__ __launch_bounds__(256) void k_gate(const float* __restrict__ x,
                                              const float* __restrict__ gw,
                                              int* __restrict__ cnt,
                                              int* __restrict__ idxl,
                                              unsigned short* __restrict__ xbf)
{
    __shared__ float gws[NEXP * DDIM];       // 32 KB
    __shared__ int lcnt[NEXP], lbase[NEXP], lofs[NEXP];
    __shared__ unsigned char selb[32];
    int tid = threadIdx.x;

    {   // stage gate_W (8x1024 f32 = 2048 float4)
        const float4* gsrc = (const float4*)gw;
        float4* gdst = (float4*)gws;
#pragma unroll
        for (int i = 0; i < 8; ++i) gdst[tid + i * 256] = gsrc[tid + i * 256];
    }
    if (tid < NEXP) { lcnt[tid] = 0; lofs[tid] = 0; }
    __syncthreads();

    int wid = tid >> 6, lane = tid & 63;
    int base_tok = blockIdx.x * 32;

    for (int s = 0; s < 8; ++s) {
        int t = base_tok + wid * 8 + s;
        const float4* rowf4 = (const float4*)(x + (size_t)t * DDIM);
        float4 xv[4];
        float acc[NEXP];
#pragma unroll
        for (int e = 0; e < NEXP; ++e) acc[e] = 0.f;
#pragma unroll
        for (int c0 = 0; c0 < 4; ++c0) {     // FULL row: 4 chunks of 64 float4
            xv[c0] = rowf4[c0 * 64 + lane];
#pragma unroll
            for (int e = 0; e < NEXP; ++e) {
                float4 g = ((const float4*)(gws + e * DDIM))[c0 * 64 + lane];
                acc[e] += xv[c0].x * g.x + xv[c0].y * g.y
                        + xv[c0].z * g.z + xv[c0].w * g.w;
            }
        }
#pragma unroll
        for (int off = 32; off >= 1; off >>= 1)
#pragma unroll
            for (int e = 0; e < NEXP; ++e) acc[e] += __shfl_xor(acc[e], off, 64);
        if (lane == 0) {
            int best = 0; float bv = acc[0];
#pragma unroll
            for (int e = 1; e < NEXP; ++e) if (acc[e] > bv) { bv = acc[e]; best = e; }
            selb[wid * 8 + s] = (unsigned char)best;    // strict > == first-max (argmax)
            atomicAdd(&lcnt[best], 1);
        }
        if (xbf) {   // uniform branch (xbf constant per launch)
#pragma unroll
            for (int c0 = 0; c0 < 4; ++c0) {
                uint2 v;
                v.x = (unsigned)f2bf(xv[c0].x) | ((unsigned)f2bf(xv[c0].y) << 16);
                v.y = (unsigned)f2bf(xv[c0].z) | ((unsigned)f2bf(xv[c0].w) << 16);
                *(uint2*)(xbf + (size_t)t * DDIM + c0 * 256 + lane * 4) = v;
            }
        }
    }
    __syncthreads();
    if (tid < NEXP) lbase[tid] = atomicAdd(&cnt[tid], lcnt[tid]);
    __syncthreads();
    if (tid < 32) {
        int e = selb[tid];
        int p = atomicAdd(&lofs[e], 1);
        idxl[e * NTOK + lbase[e] + p] = base_tok + tid;
    }
}

// ---------------------------------------------------------------------------
// Kernel 1b: W1 [E][D][H] fp32 -> W1T [E][H][D] bf16 (transpose + convert).
// ---------------------------------------------------------------------------
__global__ __launch_bounds__(256) void k_w1t(const float* __restrict__ W1,
                                             unsigned short* __restrict__ W1T)
{
    // grid: E * (D/64) * (H/64) = 1024 blocks
    int bx = blockIdx.x;
    int e = bx & 7;
    int r = bx >> 3;
    int d0 = (r & 15) * 64;
    int h0 = (r >> 4) * 64;
    __shared__ float tile[64][65];           // +1 pad breaks transpose conflicts
    int tid = threadIdx.x;
    int tr = tid >> 4;                       // 0..15
    int tc = tid & 15;                       // 0..15

    const float* src = W1 + ((size_t)e * DDIM + d0) * HDIM + h0;
#pragma unroll
    for (int p = 0; p < 4; ++p) {
        int d = tr + p * 16;
        float4 v = *(const float4*)(src + (size_t)d * HDIM + tc * 4);
        tile[d][tc * 4 + 0] = v.x;
        tile[d][tc * 4 + 1] = v.y;
        tile[d][tc * 4 + 2] = v.z;
        tile[d][tc * 4 + 3] = v.w;
    }
    __syncthreads();
    unsigned short* dst = W1T + ((size_t)e * HDIM + h0) * DDIM + d0;
#pragma unroll
    for (int p = 0; p < 4; ++p) {
        int h = tr + p * 16;
        float a = tile[tc * 4 + 0][h];
        float b = tile[tc * 4 + 1][h];
        float c = tile[tc * 4 + 2][h];
        float d = tile[tc * 4 + 3][h];
        unsigned int lo = (unsigned int)f2bf(a) | ((unsigned int)f2bf(b) << 16);
        unsigned int hi = (unsigned int)f2bf(c) | ((unsigned int)f2bf(d) << 16);
        uint2 v; v.x = lo; v.y = hi;
        *(uint2*)(dst + (size_t)h * DDIM + tc * 4) = v;
    }
}

// ---------------------------------------------------------------------------
// Kernel 2: grouped score GEMM. Block = (expert e, 64 gathered tokens), full
// H=512 in registers (tanh needs full-D accumulation per h; holding all H
// means each token row of X is read exactly once device-wide). 8 waves, wave
// tile = 64tok x 64h (4x4 of 16x16x32 bf16 MFMA). BK=64. m97-class
// single-buffer 2-barrier K-loop (dbuf neutral at this class: m99/m131-140).
// Staging via global_load_lds(16B): LDS linear dest (base wid*1024 + lane*16
// == slot (srow, scj)), XOR-swizzle applied to the per-lane GLOBAL source;
// read side applies the same XOR -> 2-way-max bank aliasing (free, m136).
// e = blockIdx%8 pins experts to XCDs (T1): W1T[e] (1MB bf16) L2-resident.
// ---------------------------------------------------------------------------
template<bool XBF>
__global__ __launch_bounds__(512, 2) void k_score(
    const float* __restrict__ x, const unsigned short* __restrict__ xbf,
    const unsigned short* __restrict__ W1T,
    const float* __restrict__ b1, const float* __restrict__ w2,
    const int* __restrict__ cnt, const int* __restrict__ idxl,
    float* __restrict__ scores)
{
    int e = blockIdx.x & 7;
    int tile = blockIdx.x >> 3;
    int c = cnt[e];
    int t0 = tile * 64;
    if (t0 >= c) return;                     // block-uniform

    __shared__ __align__(16) unsigned short Xs[64 * 64];    // 8 KB
    __shared__ __align__(16) unsigned short Ws[512 * 64];   // 64 KB
    __shared__ float sred[8][64];                           // 2 KB

    int tid = threadIdx.x;
    int wid = tid >> 6, lane = tid & 63;

    // staging geometry: 512 thr = 64 rows x 8 chunks of 8 bf16 (16 B)
    int srow = tid >> 3;                     // 0..63
    int scj  = tid & 7;                      // linear chunk slot
    int sc   = (scj ^ (srow & 7)) * 8;       // pre-swizzled SOURCE chunk (bf16 units)
    int tpos = t0 + srow;
    int tok = idxl[e * NTOK + (tpos < c ? tpos : c - 1)];   // clamp tail (not written)
    const unsigned short* wsrc =
        W1T + (size_t)e * HDIM * DDIM + (size_t)srow * DDIM + sc;
    const unsigned short* xsrc_bf = XBF ? xbf + (size_t)tok * DDIM + sc : (const unsigned short*)0;
    const float* xsrc_f = x + (size_t)tok * DDIM + scj * 8;

    // wave-uniform LDS bases: lane-linear fill (l>>3)*128 + (l&7)*16 == l*16
    char* XsB = (char*)Xs + wid * 1024;
    char* WsB = (char*)Ws + wid * 1024;

    f32x4 acc[4][4];
#pragma unroll
    for (int m = 0; m < 4; ++m)
#pragma unroll
        for (int n = 0; n < 4; ++n) acc[m][n] = (f32x4){0.f, 0.f, 0.f, 0.f};

    for (int kb = 0; kb < DDIM / 64; ++kb) {
        int kbase = kb * 64;
        if constexpr (XBF) {
            gload_lds16(xsrc_bf + kbase, XsB);
        } else {
            float4 xa = *(const float4*)(xsrc_f + kbase);
            float4 xb = *(const float4*)(xsrc_f + kbase + 4);
            short8 xv;
            xv[0] = (short)f2bf(xa.x); xv[1] = (short)f2bf(xa.y);
            xv[2] = (short)f2bf(xa.z); xv[3] = (short)f2bf(xa.w);
            xv[4] = (short)f2bf(xb.x); xv[5] = (short)f2bf(xb.y);
            xv[6] = (short)f2bf(xb.z); xv[7] = (short)f2bf(xb.w);
            *(short8*)(Xs + srow * 64 + sc) = xv;     // manual swizzled scatter
        }
#pragma unroll
        for (int p = 0; p < 8; ++p)                   // rows h = srow + p*64
            gload_lds16(wsrc + (size_t)p * 64 * DDIM + kbase, WsB + p * 8192);
        __syncthreads();                              // drains vmcnt+lgkmcnt

#pragma unroll
        for (int kk = 0; kk < 2; ++kk) {
            int cchunk = kk * 4 + (lane >> 4);
            int rlo = lane & 15;
            short8 af[4], bfr[4];
#pragma unroll
            for (int m = 0; m < 4; ++m) {
                int row = m * 16 + rlo;
                af[m] = *(const short8*)(Xs + row * 64 + ((cchunk ^ (row & 7)) * 8));
            }
#pragma unroll
            for (int n = 0; n < 4; ++n) {
                int h = wid * 64 + n * 16 + rlo;
                bfr[n] = *(const short8*)(Ws + h * 64 + ((cchunk ^ (h & 7)) * 8));
            }
#pragma unroll
            for (int m = 0; m < 4; ++m)
#pragma unroll
                for (int n = 0; n < 4; ++n)
                    acc[m][n] = __builtin_amdgcn_mfma_f32_16x16x32_bf16(
                        af[m], bfr[n], acc[m][n], 0, 0, 0);
        }
        __syncthreads();
    }

    // epilogue: score[tok] = sum_h tanh(acc + b1[h]) * w2[h]
    // C/D layout (m89): col(h) = lane&15, row(tok) = (lane>>4)*4 + reg
    int hl = lane & 15, hg = lane >> 4;
    float sp[4][4];
#pragma unroll
    for (int m = 0; m < 4; ++m)
#pragma unroll
        for (int r = 0; r < 4; ++r) sp[m][r] = 0.f;
#pragma unroll
    for (int n = 0; n < 4; ++n) {
        int hcol = wid * 64 + n * 16 + hl;
        float b1v = b1[e * HDIM + hcol];
        float w2v = w2[e * HDIM + hcol];
#pragma unroll
        for (int m = 0; m < 4; ++m)
#pragma unroll
            for (int r = 0; r < 4; ++r)
                sp[m][r] += fast_tanh(acc[m][n][r] + b1v) * w2v;
    }
#pragma unroll
    for (int off = 1; off < 16; off <<= 1)   // reduce over hl (same-hg lanes)
#pragma unroll
        for (int m = 0; m < 4; ++m)
#pragma unroll
            for (int r = 0; r < 4; ++r)
                sp[m][r] += __shfl_xor(sp[m][r], off, 64);
    if (hl == 0) {
#pragma unroll
        for (int m = 0; m < 4; ++m)
#pragma unroll
            for (int r = 0; r < 4; ++r)
                sred[wid][m * 16 + hg * 4 + r] = sp[m][r];
    }
    __syncthreads();
    if (tid < 64 && t0 + tid < c) {
        float s = 0.f;
#pragma unroll
        for (int w = 0; w < 8; ++w) s += sred[w][tid];
        scores[e * NTOK + t0 + tid] = s;     // b2 omitted: softmax shift-invariant
    }
}

// ---------------------------------------------------------------------------
// Kernel 3: per-expert softmax stats (max, 1/sum-exp). One block per expert.
// ---------------------------------------------------------------------------
__global__ __launch_bounds__(256) void k_stats(const float* __restrict__ scores,
                                               const int* __restrict__ cnt,
                                               float* __restrict__ mbuf,
                                               float* __restrict__ invl)
{
    int e = blockIdx.x;
    int c = cnt[e];
    __shared__ float red[8];
    int tid = threadIdx.x, wid = tid >> 6, lane = tid & 63;
    const float* s = scores + (size_t)e * NTOK;

    float mx = -3.4e38f;
    for (int p = tid; p < c; p += 256) mx = fmaxf(mx, s[p]);
#pragma unroll
    for (int off = 32; off >= 1; off >>= 1) mx = fmaxf(mx, __shfl_xor(mx, off, 64));
    if (lane == 0) red[wid] = mx;
    __syncthreads();
    mx = fmaxf(fmaxf(red[0], red[1]), fmaxf(red[2], red[3]));
    __syncthreads();

    float sm = 0.f;
    for (int p = tid; p < c; p += 256) sm += expf(s[p] - mx);
#pragma unroll
    for (int off = 32; off >= 1; off >>= 1) sm += __shfl_xor(sm, off, 64);
    if (lane == 0) red[4 + wid] = sm;
    __syncthreads();
    if (tid == 0) {
        float l = red[4] + red[5] + red[6] + red[7];
        mbuf[e] = mx;
        invl[e] = (c > 0 && l > 0.f) ? 1.0f / l : 0.f;
    }
}

// ---------------------------------------------------------------------------
// Kernel 4: pooled[e] = sum_n attn[n] * x[n]. 256-token chunks; weights in
// LDS (broadcast reads); each thread owns 4 feature dims; fp32 X (L3-warm
// after k_gate). unroll 4 -> 4 independent row loads in flight per thread.
// ---------------------------------------------------------------------------
__global__ __launch_bounds__(256) void k_pool(const float* __restrict__ x,
                                              const float* __restrict__ scores,
                                              const int* __restrict__ idxl,
                                              const int* __restrict__ cnt,
                                              const float* __restrict__ mbuf,
                                              const float* __restrict__ invl,
                                              float* __restrict__ out)
{
    int e = blockIdx.x & 7;
    int ch = blockIdx.x >> 3;
    int c = cnt[e];
    int start = ch * 256;
    if (start >= c) return;
    int nt = min(256, c - start);

    __shared__ float wls[256];
    __shared__ int nls[256];
    int tid = threadIdx.x;
    if (tid < nt) {
        wls[tid] = expf(scores[(size_t)e * NTOK + start + tid] - mbuf[e]) * invl[e];
        nls[tid] = idxl[e * NTOK + start + tid];
    }
    __syncthreads();

    float4 a = {0.f, 0.f, 0.f, 0.f};
#pragma unroll 4
    for (int t = 0; t < nt; ++t) {
        float w = wls[t];
        float4 xv = *(const float4*)(x + (size_t)nls[t] * DDIM + tid * 4);
        a.x += w * xv.x; a.y += w * xv.y; a.z += w * xv.z; a.w += w * xv.w;
    }
    float* o = out + e * DDIM + tid * 4;
    atomicAdd(o + 0, a.x);
    atomicAdd(o + 1, a.y);
    atomicAdd(o + 2, a.z);
    atomicAdd(o + 3, a.w);
}

// ---------------------------------------------------------------------------
extern "C" void kernel_launch(void* const* d_in, const int* in_sizes, int n_in,
                              void* d_out, int out_size, void* d_ws, size_t ws_size,
                              hipStream_t stream) {
    const float* x  = (const float*)d_in[0];   // [N, D]
    const float* gw = (const float*)d_in[1];   // [E, D]
    const float* W1 = (const float*)d_in[2];   // [E, D, H]
    const float* b1 = (const float*)d_in[3];   // [E, H]
    const float* w2 = (const float*)d_in[4];   // [E, H]
    // d_in[5] = b2: provably unused (softmax shift invariance)
    float* out = (float*)d_out;                // [E*D] = 8192 f32

    char* ws = (char*)d_ws;
    size_t off = 0;
    int* cnt = (int*)(ws + off);               off += 256;
    int* idxl = (int*)(ws + off);              off += (size_t)NEXP * NTOK * 4;  // 1 MB
    float* scores = (float*)(ws + off);        off += (size_t)NEXP * NTOK * 4;  // 1 MB
    float* mbuf = (float*)(ws + off);
    float* invl = mbuf + NEXP;                 off += 256;
    unsigned short* W1T = (unsigned short*)(ws + off);
    off += (size_t)NEXP * HDIM * DDIM * 2;     // 8 MB
    size_t xbf_off = off;
    size_t need_xbf = off + (size_t)NTOK * DDIM * 2;   // +64 MB
    bool use_xbf = (ws_size >= need_xbf);      // ws_size constant across calls -> graph-safe
    unsigned short* xbf = use_xbf ? (unsigned short*)(ws + xbf_off) : nullptr;

    hipMemsetAsync(cnt, 0, NEXP * sizeof(int), stream);
    hipMemsetAsync(d_out, 0, (size_t)NEXP * DDIM * sizeof(float), stream);

    k_gate <<<NTOK / 32, 256, 0, stream>>>(x, gw, cnt, idxl, xbf);
    k_w1t  <<<NEXP * (DDIM / 64) * (HDIM / 64), 256, 0, stream>>>(W1, W1T);
    if (use_xbf)
        k_score<true><<<NEXP * (NTOK / 64), 512, 0, stream>>>(x, xbf, W1T, b1, w2, cnt, idxl, scores);
    else
        k_score<false><<<NEXP * (NTOK / 64), 512, 0, stream>>>(x, xbf, W1T, b1, w2, cnt, idxl, scores);
    k_stats<<<NEXP, 256, 0, stream>>>(scores, cnt, mbuf, invl);
    k_pool <<<NEXP * (NTOK / 256), 256, 0, stream>>>(x, scores, idxl, cnt, mbuf, invl, out);
}